// Round 1
// baseline (880.583 us; speedup 1.0000x reference)
//
#include <hip/hip_runtime.h>
#include <stdint.h>

typedef __bf16 bf16;
typedef bf16 bf16x8 __attribute__((ext_vector_type(8)));
typedef float f32x4 __attribute__((ext_vector_type(4)));
typedef unsigned short u16x8 __attribute__((ext_vector_type(8)));

// ---------------------------------------------------------------------------
// Prep: convert+transpose weights w1..w12 from fp32 (O,C,K) to bf16 [O][K*C]
// (r = k*C + c ordering, so a 32-chunk of r is one k, 32 contiguous c)
// ---------------------------------------------------------------------------
template<int C>
__device__ inline void cvt_one(const float* __restrict__ src, bf16* __restrict__ dst,
                               int e, int base) {
    int local = e - base;
    constexpr int CK = C * 10;
    int o = local / CK;
    int rem = local - o * CK;
    int k = rem / C;          // C is power of two -> shift
    int c = rem & (C - 1);
    dst[e] = (bf16)src[(o * C + c) * 10 + k];
}

__global__ __launch_bounds__(256) void prep_w(
    const float* w1, const float* w2, const float* w3, const float* w4,
    const float* w5, const float* w6, const float* w7, const float* w8,
    const float* w9, const float* w10, const float* w11, const float* w12,
    bf16* __restrict__ dst)
{
    int e = blockIdx.x * 256 + threadIdx.x;
    if (e >= 16343040) return;
    if      (e <    40960) cvt_one< 64>(w1,  dst, e, 0);
    else if (e <   122880) cvt_one< 64>(w2,  dst, e, 40960);
    else if (e <   286720) cvt_one<128>(w3,  dst, e, 122880);
    else if (e <   614400) cvt_one<128>(w4,  dst, e, 286720);
    else if (e <  1269760) cvt_one<256>(w5,  dst, e, 614400);
    else if (e <  1925120) cvt_one<256>(w6,  dst, e, 1269760);
    else if (e <  3235840) cvt_one<256>(w7,  dst, e, 1925120);
    else if (e <  5857280) cvt_one<512>(w8,  dst, e, 3235840);
    else if (e <  8478720) cvt_one<512>(w9,  dst, e, 5857280);
    else if (e < 11100160) cvt_one<512>(w10, dst, e, 8478720);
    else if (e < 13721600) cvt_one<512>(w11, dst, e, 11100160);
    else                   cvt_one<512>(w12, dst, e, 13721600);
}

// ---------------------------------------------------------------------------
// conv0: C=3, K=10, O=64, fp32 VALU. x is (2,3,81920) fp32. out: [2][81920][64] bf16
// ---------------------------------------------------------------------------
__global__ __launch_bounds__(256) void conv0_kernel(
    const float* __restrict__ x, const float* __restrict__ w0,
    const float* __restrict__ b0, const int* __restrict__ table,
    bf16* __restrict__ out)
{
    const int N = 81920;
    __shared__ float wls[30][64];   // [c*10+k][o]
    __shared__ float bls[64];
    int tid = threadIdx.x;
    for (int i = tid; i < 1920; i += 256) {
        int o = i / 30, ck = i - o * 30;
        wls[ck][o] = w0[i];
    }
    if (tid < 64) bls[tid] = b0[tid];
    __syncthreads();

    int p = blockIdx.x * 256 + tid;       // [0, 163840)
    int b = p >= N;
    int n = p - b * N;
    int idx[10];
    const int* trow = table + n * 10;
#pragma unroll
    for (int k = 0; k < 10; k++) idx[k] = trow[k];
    float xv[30];
#pragma unroll
    for (int c = 0; c < 3; c++)
#pragma unroll
        for (int k = 0; k < 10; k++)
            xv[c * 10 + k] = x[(b * 3 + c) * N + idx[k]];

    float acc[64];
#pragma unroll
    for (int o = 0; o < 64; o++) acc[o] = bls[o];
    for (int ck = 0; ck < 30; ck++) {
        float xs = xv[ck];
        const f32x4* wrow = (const f32x4*)(&wls[ck][0]);
#pragma unroll
        for (int o4 = 0; o4 < 16; o4++) {
            f32x4 w4 = wrow[o4];
            acc[o4 * 4 + 0] += xs * w4[0];
            acc[o4 * 4 + 1] += xs * w4[1];
            acc[o4 * 4 + 2] += xs * w4[2];
            acc[o4 * 4 + 3] += xs * w4[3];
        }
    }
    bf16x8 ob[8];
#pragma unroll
    for (int i = 0; i < 8; i++)
#pragma unroll
        for (int e = 0; e < 8; e++)
            ob[i][e] = (bf16)fmaxf(acc[i * 8 + e], 0.0f);
    bf16x8* dst = (bf16x8*)(out + (size_t)p * 64);
#pragma unroll
    for (int i = 0; i < 8; i++) dst[i] = ob[i];
}

// ---------------------------------------------------------------------------
// Main conv: gathered GEMM with MFMA 16x16x32 bf16.
// in:  [2][N][C] bf16   w: [O][K*C] bf16 (r=k*C+c)   out: [2][N][O] bf16
// Block tile: BO (out ch) x BP (positions), 4 waves as 2x2,
// per-wave (BO/32)x(BP/32) MFMA tiles of 16x16. Requires C%32==0, (2N)%BP==0.
// ---------------------------------------------------------------------------
template<int BO, int BP>
__global__ __launch_bounds__(256) void conv_mfma(
    const bf16* __restrict__ in, const bf16* __restrict__ w,
    const float* __restrict__ bias, const int* __restrict__ table,
    bf16* __restrict__ out, int N, int C, int O)
{
    constexpr int TO = BO / 32;
    constexpr int TP = BP / 32;
    constexpr int STR = 40;                    // padded LDS row stride (bf16)
    __shared__ bf16 Xs[BP][STR];
    __shared__ bf16 Ws[BO][STR];
    __shared__ int rowoff[BP][10];             // pre-multiplied gather row offsets

    const int tid = threadIdx.x;
    const int p0 = blockIdx.x * BP;
    const int o0 = blockIdx.y * BO;
    const int CK = C * 10;

    for (int j = tid; j < BP * 10; j += 256) {
        int pp = j / 10, k = j - pp * 10;
        int p = p0 + pp;
        int b = p >= N;
        int n = p - b * N;
        rowoff[pp][k] = (b * N + table[n * 10 + k]) * C;
    }
    __syncthreads();

    const int lane = tid & 63;
    const int wid = tid >> 6;
    const int wo = wid & 1, wp = wid >> 1;
    const int q = lane >> 4, l16 = lane & 15;

    f32x4 acc[TO][TP];
#pragma unroll
    for (int a = 0; a < TO; a++)
#pragma unroll
        for (int c = 0; c < TP; c++) acc[a][c] = (f32x4){0.f, 0.f, 0.f, 0.f};

    int k = 0, c0 = 0;
    const int chunks = CK / 32;
    for (int kt = 0; kt < chunks; ++kt) {
        // stage gathered X chunk: BP rows x 32 bf16 (64B contiguous per row)
        {
            constexpr int LOADS = BP * 4 / 256;
#pragma unroll
            for (int i = 0; i < LOADS; ++i) {
                int li = tid + i * 256;
                int pp = li >> 2, seg = li & 3;
                uint4 v = *(const uint4*)(in + rowoff[pp][k] + c0 + seg * 8);
                *(uint4*)(&Xs[pp][seg * 8]) = v;
            }
        }
        // stage W chunk: BO rows x 32 bf16
        {
            constexpr int LOADSW = BO * 4 / 256;
#pragma unroll
            for (int i = 0; i < LOADSW; ++i) {
                int li = tid + i * 256;
                int oo = li >> 2, seg = li & 3;
                uint4 v = *(const uint4*)(w + (size_t)(o0 + oo) * CK + kt * 32 + seg * 8);
                *(uint4*)(&Ws[oo][seg * 8]) = v;
            }
        }
        __syncthreads();

        bf16x8 af[TO], bfr[TP];
#pragma unroll
        for (int t = 0; t < TO; t++)
            af[t] = *(const bf16x8*)(&Ws[wo * (BO / 2) + t * 16 + l16][q * 8]);
#pragma unroll
        for (int t = 0; t < TP; t++)
            bfr[t] = *(const bf16x8*)(&Xs[wp * (BP / 2) + t * 16 + l16][q * 8]);
#pragma unroll
        for (int to = 0; to < TO; to++)
#pragma unroll
            for (int tp = 0; tp < TP; tp++)
                acc[to][tp] = __builtin_amdgcn_mfma_f32_16x16x32_bf16(
                    af[to], bfr[tp], acc[to][tp], 0, 0, 0);
        __syncthreads();

        c0 += 32;
        if (c0 == C) { c0 = 0; ++k; }
    }

    // epilogue: bias + relu + pack 4 consecutive o as 8B store
#pragma unroll
    for (int to = 0; to < TO; ++to) {
        int ob = o0 + wo * (BO / 2) + to * 16 + q * 4;
        f32x4 bv = *(const f32x4*)(bias + ob);
#pragma unroll
        for (int tp = 0; tp < TP; ++tp) {
            int p = p0 + wp * (BP / 2) + tp * 16 + l16;
            union { ushort4 u4; unsigned short s[4]; } pk;
#pragma unroll
            for (int r = 0; r < 4; r++) {
                float v = fmaxf(acc[to][tp][r] + bv[r], 0.0f);
                union { bf16 h; unsigned short u; } cc;
                cc.h = (bf16)v;
                pk.s[r] = cc.u;
            }
            *(ushort4*)(out + (size_t)p * O + ob) = pk.u4;
        }
    }
}

// ---------------------------------------------------------------------------
// Maxpool: out[b][j][c] = max_i in[b][adj[pool[j]][i]][c]; bf16, post-ReLU so
// unsigned-short compare == float compare. c8shift = log2(C/8).
// ---------------------------------------------------------------------------
__global__ __launch_bounds__(256) void pool_kernel(
    const bf16* __restrict__ in, const int* __restrict__ adj,
    const int* __restrict__ pool, bf16* __restrict__ out,
    int N, int M, int c8shift)
{
    int t = blockIdx.x * 256 + threadIdx.x;
    int total = M << c8shift;
    if (t >= total) return;
    int cc = t & ((1 << c8shift) - 1);
    int j = t >> c8shift;
    int b = blockIdx.y;
    int C = 8 << c8shift;
    int s = pool[j];
    const int* a = adj + s * 4;
    const unsigned short* inu = (const unsigned short*)in;
    size_t base = (size_t)b * N * C + (size_t)cc * 8;
    u16x8 m = *(const u16x8*)(inu + base + (size_t)a[0] * C);
#pragma unroll
    for (int i = 1; i < 4; i++) {
        u16x8 v = *(const u16x8*)(inu + base + (size_t)a[i] * C);
#pragma unroll
        for (int e = 0; e < 8; e++) m[e] = v[e] > m[e] ? v[e] : m[e];
    }
    *(u16x8*)((unsigned short*)out + ((size_t)b * M + j) * C + (size_t)cc * 8) = m;
}

// Final pool: in [2][320][512] bf16 -> out (2,512,80) fp32 (reference layout)
__global__ __launch_bounds__(256) void final_pool(
    const bf16* __restrict__ in, const int* __restrict__ adj,
    const int* __restrict__ pool, float* __restrict__ out)
{
    int t = blockIdx.x * 256 + threadIdx.x;   // 2*512*80 = 81920
    if (t >= 81920) return;
    int j = t % 80;
    int rest = t / 80;
    int c = rest & 511;
    int b = rest >> 9;
    int s = pool[j];
    const int* a = adj + s * 4;
    float m = 0.0f;   // activations are post-ReLU, >= 0
#pragma unroll
    for (int i = 0; i < 4; i++) {
        float v = (float)in[((size_t)b * 320 + a[i]) * 512 + c];
        m = fmaxf(m, v);
    }
    out[t] = m;
}

// ---------------------------------------------------------------------------
extern "C" void kernel_launch(void* const* d_in, const int* in_sizes, int n_in,
                              void* d_out, int out_size, void* d_ws, size_t ws_size,
                              hipStream_t stream)
{
    const float* x = (const float*)d_in[0];
    const int* convT[5]; const int* adjT[5]; const int* poolT[5];
    for (int l = 0; l < 5; l++) {
        convT[l] = (const int*)d_in[1 + 3 * l];
        adjT[l]  = (const int*)d_in[2 + 3 * l];
        poolT[l] = (const int*)d_in[3 + 3 * l];
    }
    const float* W[13]; const float* Bs[13];
    for (int i = 0; i < 13; i++) {
        W[i]  = (const float*)d_in[16 + 2 * i];
        Bs[i] = (const float*)d_in[17 + 2 * i];
    }

    // workspace: [bf16 weights w1..w12 | buf A | buf B]
    bf16* wbf = (bf16*)d_ws;
    bf16* A  = (bf16*)((char*)d_ws + (size_t)16343040 * 2);   // 32,686,080 B
    bf16* Bb = A + 10485760;                                   // 2*81920*64 elems

    static const int woff[13] = {0, 0, 40960, 122880, 286720, 614400, 1269760,
                                 1925120, 3235840, 5857280, 8478720, 11100160, 13721600};

    prep_w<<<dim3((16343040 + 255) / 256), dim3(256), 0, stream>>>(
        W[1], W[2], W[3], W[4], W[5], W[6], W[7], W[8], W[9], W[10], W[11], W[12], wbf);

    conv0_kernel<<<dim3(640), dim3(256), 0, stream>>>(x, W[0], Bs[0], convT[0], A);

    // level 0
    conv_mfma<64,128><<<dim3(1280, 1), dim3(256), 0, stream>>>(A, wbf + woff[1], Bs[1], convT[0], Bb, 81920, 64, 64);
    pool_kernel<<<dim3(640, 2), dim3(256), 0, stream>>>(Bb, adjT[0], poolT[0], A, 81920, 20480, 3);
    // level 1
    conv_mfma<128,128><<<dim3(320, 1), dim3(256), 0, stream>>>(A, wbf + woff[2], Bs[2], convT[1], Bb, 20480, 64, 128);
    conv_mfma<128,128><<<dim3(320, 1), dim3(256), 0, stream>>>(Bb, wbf + woff[3], Bs[3], convT[1], A, 20480, 128, 128);
    pool_kernel<<<dim3(320, 2), dim3(256), 0, stream>>>(A, adjT[1], poolT[1], Bb, 20480, 5120, 4);
    // level 2
    conv_mfma<64,128><<<dim3(80, 4), dim3(256), 0, stream>>>(Bb, wbf + woff[4], Bs[4], convT[2], A, 5120, 128, 256);
    conv_mfma<64,128><<<dim3(80, 4), dim3(256), 0, stream>>>(A, wbf + woff[5], Bs[5], convT[2], Bb, 5120, 256, 256);
    conv_mfma<64,128><<<dim3(80, 4), dim3(256), 0, stream>>>(Bb, wbf + woff[6], Bs[6], convT[2], A, 5120, 256, 256);
    pool_kernel<<<dim3(160, 2), dim3(256), 0, stream>>>(A, adjT[2], poolT[2], Bb, 5120, 1280, 5);
    // level 3
    conv_mfma<64,64><<<dim3(40, 8), dim3(256), 0, stream>>>(Bb, wbf + woff[7], Bs[7], convT[3], A, 1280, 256, 512);
    conv_mfma<64,64><<<dim3(40, 8), dim3(256), 0, stream>>>(A, wbf + woff[8], Bs[8], convT[3], Bb, 1280, 512, 512);
    conv_mfma<64,64><<<dim3(40, 8), dim3(256), 0, stream>>>(Bb, wbf + woff[9], Bs[9], convT[3], A, 1280, 512, 512);
    pool_kernel<<<dim3(80, 2), dim3(256), 0, stream>>>(A, adjT[3], poolT[3], Bb, 1280, 320, 6);
    // level 4
    conv_mfma<64,64><<<dim3(10, 8), dim3(256), 0, stream>>>(Bb, wbf + woff[10], Bs[10], convT[4], A, 320, 512, 512);
    conv_mfma<64,64><<<dim3(10, 8), dim3(256), 0, stream>>>(A, wbf + woff[11], Bs[11], convT[4], Bb, 320, 512, 512);
    conv_mfma<64,64><<<dim3(10, 8), dim3(256), 0, stream>>>(Bb, wbf + woff[12], Bs[12], convT[4], A, 320, 512, 512);

    final_pool<<<dim3(320), dim3(256), 0, stream>>>(A, adjT[4], poolT[4], (float*)d_out);
}